// Round 2
// 794.913 us; speedup vs baseline: 1.1430x; 1.1430x over previous
//
#include <hip/hip_runtime.h>
#include <stdint.h>

// ============================================================================
// LoRA Multihead Attention, MI355X / gfx950.  Round 11 (R10 resubmit).
// R10 bench died to container acquisition failure (no kernel verdict).
// Identical structure; amdgpu_waves_per_eu(4) min-only form (the max bound
// was the only untested attribute variant and adds nothing for regalloc).
//
// R9 post-mortem: VGPR_Count=64 with ~670 MB excess WRITE_SIZE -> compiler
// allocated for 8 waves/SIMD (2 blocks/CU) that the 256-block grid never
// provides, spilling sacc/wmean to scratch.  launch_bounds 2nd arg ignored
// (R8).  Fix: (a) amdgpu_waves_per_eu(4) forces the 128-VGPR budget that
// matches the real 1-block/CU residency; (b) wlds widened to full row
// (16x2056) so each wave writes/PV-reads ONLY its own 128-wide j-slice:
// sacc dead before PV (-32 live regs), write->PV needs NO barrier
// (same-wave LDS RAW is in-order), 8 -> 6 barriers/head; (c) fm hoisted.
// Predict: WRITE_SIZE 713->~45 MB, attn 570 -> ~250 us.
// ============================================================================

typedef __attribute__((ext_vector_type(8))) short short8;   // 8 x bf16 (4 VGPR)
typedef __attribute__((ext_vector_type(4))) float f32x4;    // MFMA C/D

#define LORA_SCALING 4.0f   // ALPHA/R = 32/8
#define FTINY 1.1754943508222875e-38f

static __device__ __forceinline__ unsigned short f2bf(float f){ // RN-even
  unsigned u = __float_as_uint(f);
  u += 0x7fffu + ((u >> 16) & 1u);
  return (unsigned short)(u >> 16);
}
static __device__ __forceinline__ float bflo(unsigned u){ return __uint_as_float(u << 16); }
static __device__ __forceinline__ float bfhi(unsigned u){ return __uint_as_float(u & 0xffff0000u); }
static __device__ __forceinline__ unsigned pk2(float lo, float hi){
  return (unsigned)f2bf(lo) | ((unsigned)f2bf(hi) << 16);
}

// ---------------------------------------------------------------------------
// xa[t][r] = sum_i x[t][i] * A[r][i]   (fp32 out), K=1024, R=8.
// ---------------------------------------------------------------------------
__global__ __launch_bounds__(256) void xa_kernel(const void* __restrict__ Xv,
                                                 const float* __restrict__ A,
                                                 float* __restrict__ xa, int xint)
{
  __shared__ float red[4][8];
  const int t = blockIdx.x, tid = threadIdx.x;
  const int lane = tid & 63, wid = tid >> 6;

  float x0, x1, x2, x3;
  if (!xint) {
    const float4 xr = *(const float4*)((const float*)Xv + (size_t)t*1024 + tid*4);
    x0 = xr.x; x1 = xr.y; x2 = xr.z; x3 = xr.w;
  } else {
    const uint2 xr = *(const uint2*)((const unsigned short*)Xv + (size_t)t*1024 + tid*4);
    x0 = bflo(xr.x); x1 = bfhi(xr.x); x2 = bflo(xr.y); x3 = bfhi(xr.y);
  }
  float acc[8];
#pragma unroll
  for (int r = 0; r < 8; ++r) {
    const float4 ar = *(const float4*)(A + (size_t)r*1024 + tid*4);
    acc[r] = x0*ar.x + x1*ar.y + x2*ar.z + x3*ar.w;
  }
#pragma unroll
  for (int r = 0; r < 8; ++r) {
    float v = acc[r];
#pragma unroll
    for (int off = 32; off > 0; off >>= 1) v += __shfl_xor(v, off, 64);
    if (lane == 0) red[wid][r] = v;
  }
  __syncthreads();
  if (tid < 8) xa[(size_t)t*8 + tid] = red[0][tid] + red[1][tid] + red[2][tid] + red[3][tid];
}

// ---------------------------------------------------------------------------
// C = X(4096xK) * W(NxK)^T + bias + 4 * xa * Blora^T.  MFMA 16x16x32,
// 128x128 tile, BK=32, plain LDS staging.  z picks parameter set.
// z==2 writes bf16 output in transposed Vt layout.  fp32out: write fp32.
// ---------------------------------------------------------------------------
__global__ __launch_bounds__(256) void gemm_fused(
    const void* __restrict__ Xv,
    const float* __restrict__ W0, const float* __restrict__ W1, const float* __restrict__ W2,
    const float* __restrict__ B0, const float* __restrict__ B1, const float* __restrict__ B2,
    const float* __restrict__ xa0, const float* __restrict__ xa1, const float* __restrict__ xa2,
    const float* __restrict__ L0, const float* __restrict__ L1, const float* __restrict__ L2,
    void* __restrict__ C0, void* __restrict__ C1, void* __restrict__ C2,
    int xint, int fp32out)
{
  const int z = blockIdx.z;
  const float* W  = (z==0)?W0:((z==1)?W1:W2);
  const float* Bb = (z==0)?B0:((z==1)?B1:B2);
  const float* xa = (z==0)?xa0:((z==1)?xa1:xa2);
  const float* Lb = (z==0)?L0:((z==1)?L1:L2);
  void*        C  = (z==0)?C0:((z==1)?C1:C2);
  const bool vtw = (z == 2);

  __shared__ alignas(16) unsigned short As[128*32];
  __shared__ alignas(16) unsigned short Bs[128*32];

  const int tid = threadIdx.x;
  const int lane = tid & 63, wid = tid >> 6;
  const int quad = lane >> 4, lm = lane & 15;
  const int t0 = blockIdx.x * 128, n0 = blockIdx.y * 128;
  const int wm = (wid & 1) * 64, wn = (wid >> 1) * 64;

  const int srow = tid >> 1;            // 0..127
  const int shalf = (tid & 1) * 16;     // 0 or 16

  f32x4 acc[4][4];
#pragma unroll
  for (int i = 0; i < 4; ++i)
#pragma unroll
    for (int j = 0; j < 4; ++j) acc[i][j] = 0.f;

  for (int kt = 0; kt < 32; ++kt) {
    const int k0 = kt * 32;
    uint4 a0, a1, b0, b1;
    if (!xint) {
      const float* g = (const float*)Xv + (size_t)(t0 + srow)*1024 + k0 + shalf;
      const float4 f0 = ((const float4*)g)[0], f1 = ((const float4*)g)[1],
                   f2 = ((const float4*)g)[2], f3 = ((const float4*)g)[3];
      a0 = make_uint4(pk2(f0.x,f0.y), pk2(f0.z,f0.w), pk2(f1.x,f1.y), pk2(f1.z,f1.w));
      a1 = make_uint4(pk2(f2.x,f2.y), pk2(f2.z,f2.w), pk2(f3.x,f3.y), pk2(f3.z,f3.w));
    } else {
      const unsigned short* g = (const unsigned short*)Xv + (size_t)(t0 + srow)*1024 + k0 + shalf;
      a0 = *(const uint4*)g;
      a1 = *(const uint4*)(g + 8);
    }
    {
      const float* g = W + (size_t)(n0 + srow)*1024 + k0 + shalf;
      const float4 f0 = ((const float4*)g)[0], f1 = ((const float4*)g)[1],
                   f2 = ((const float4*)g)[2], f3 = ((const float4*)g)[3];
      b0 = make_uint4(pk2(f0.x,f0.y), pk2(f0.z,f0.w), pk2(f1.x,f1.y), pk2(f1.z,f1.w));
      b1 = make_uint4(pk2(f2.x,f2.y), pk2(f2.z,f2.w), pk2(f3.x,f3.y), pk2(f3.z,f3.w));
    }
    __syncthreads();   // previous iteration's fragment reads complete
    *(uint4*)&As[srow*32 + shalf]     = a0;
    *(uint4*)&As[srow*32 + shalf + 8] = a1;
    *(uint4*)&Bs[srow*32 + shalf]     = b0;
    *(uint4*)&Bs[srow*32 + shalf + 8] = b1;
    __syncthreads();   // stores visible
    short8 a[4], b[4];
#pragma unroll
    for (int i = 0; i < 4; ++i) a[i] = *(const short8*)&As[(wm + i*16 + lm)*32 + quad*8];
#pragma unroll
    for (int j = 0; j < 4; ++j) b[j] = *(const short8*)&Bs[(wn + j*16 + lm)*32 + quad*8];
#pragma unroll
    for (int i = 0; i < 4; ++i)
#pragma unroll
      for (int j = 0; j < 4; ++j)
        acc[i][j] = __builtin_amdgcn_mfma_f32_16x16x32_bf16(a[i], b[j], acc[i][j], 0, 0, 0);
  }

  // epilogue: bias + 4.0 * (xa . Blora)
#pragma unroll
  for (int j = 0; j < 4; ++j) {
    const int col = n0 + wn + j*16 + lm;
    const float bias = Bb[col];
    const float4 u0 = ((const float4*)(Lb + (size_t)col*8))[0];
    const float4 u1 = ((const float4*)(Lb + (size_t)col*8))[1];
#pragma unroll
    for (int i = 0; i < 4; ++i) {
#pragma unroll
      for (int r = 0; r < 4; ++r) {
        const int row = t0 + wm + i*16 + quad*4 + r;
        const float* xr = xa + (size_t)row*8;
        const float lora = xr[0]*u0.x + xr[1]*u0.y + xr[2]*u0.z + xr[3]*u0.w
                         + xr[4]*u1.x + xr[5]*u1.y + xr[6]*u1.z + xr[7]*u1.w;
        const float val = acc[i][j][r] + bias + LORA_SCALING*lora;
        if (fp32out) {
          ((float*)C)[(size_t)row*1024 + col] = val;
        } else if (vtw) {
          // t = l*2 + n  ->  Vt[(n*1024 + e)*2048 + l]
          ((unsigned short*)C)[((size_t)(row & 1) * 1024 + col) * 2048 + (row >> 1)] = f2bf(val);
        } else {
          ((unsigned short*)C)[(size_t)row*1024 + col] = f2bf(val);
        }
      }
    }
  }
}

// ---------------------------------------------------------------------------
// Fused masked attention + head-mean weights.  1024 threads = 16 waves,
// each wave owns a 128-wide j-slice.  amdgpu_waves_per_eu(4): block is
// 16 waves = 4/SIMD and grid is 1 block/CU, so budget regalloc for exactly
// that (<=128 VGPR) instead of the 64-VGPR/8-wave target that caused ~670 MB
// of scratch spill traffic in R9.
// wlds holds the FULL 16x2048 w-tile; wave wid writes cols
// [wid*128, wid*128+128) and PV reads back the same cols -> wave-local,
// no barrier between w-write and PV (same-wave LDS ops are in order).
// ctx aliases qb (safe: head h writes cols h*64.., reads cols h*64.. only).
// ---------------------------------------------------------------------------
__global__ __launch_bounds__(1024) __attribute__((amdgpu_waves_per_eu(4)))
void attn_kernel(
    const unsigned short* qb, const unsigned short* __restrict__ kb,
    const unsigned short* __restrict__ vt, const int* __restrict__ mask,
    unsigned short* ctx, float* __restrict__ wout)
{
  __shared__ alignas(16) unsigned short wlds[16*2056]; // bf16 w, full row + pad
  __shared__ float ored[8*16*68];                      // PV partials (8 sets)
  __shared__ float redA[16*16];                        // row-max staging
  __shared__ float redB[16*16];                        // row-sum staging
  __shared__ unsigned char mflag[2048];

  const int tid = threadIdx.x, lane = tid & 63, wid = tid >> 6;  // wid 0..15
  const int quad = lane >> 4, lm = lane & 15;
  const int q0 = blockIdx.x * 16, n = blockIdx.y;
  const int jbase = wid * 128;

  { const int2 m2 = *(const int2*)(mask + n*2048 + tid*2);
    mflag[tid*2+0] = (m2.x != 0); mflag[tid*2+1] = (m2.y != 0); }

  float wmean[32];
#pragma unroll
  for (int i = 0; i < 32; ++i) wmean[i] = 0.f;
  __syncthreads();

  // mask bits for this thread's j-columns: head-invariant, hoisted
  unsigned fm = 0;
#pragma unroll
  for (int t = 0; t < 8; ++t) fm |= ((unsigned)mflag[jbase + t*16 + lm]) << t;

  for (int h = 0; h < 16; ++h) {
    // ---- logits S = Q K^T (raw; 0.125 scale folded into exp) ----
    const size_t qrow = ((size_t)(q0+lm)*2 + n)*1024 + h*64 + quad*8;
    const short8 aq0 = *(const short8*)(qb + qrow);
    const short8 aq1 = *(const short8*)(qb + qrow + 32);
    f32x4 sacc[8];
#pragma unroll
    for (int t = 0; t < 8; ++t) {
      const unsigned short* kr = kb + ((size_t)(jbase + t*16 + lm)*2 + n)*1024 + h*64 + quad*8;
      const short8 b0 = *(const short8*)kr;
      const short8 b1 = *(const short8*)(kr + 32);
      f32x4 c; c = 0.f;
      c = __builtin_amdgcn_mfma_f32_16x16x32_bf16(aq0, b0, c, 0, 0, 0);
      c = __builtin_amdgcn_mfma_f32_16x16x32_bf16(aq1, b1, c, 0, 0, 0);
      sacc[t] = c;
    }

    // ---- row max over unmasked ----
    float mymax[4] = {-3.0e38f, -3.0e38f, -3.0e38f, -3.0e38f};
#pragma unroll
    for (int t = 0; t < 8; ++t)
      if (!((fm >> t) & 1)) {
#pragma unroll
        for (int r = 0; r < 4; ++r) mymax[r] = fmaxf(mymax[r], sacc[t][r]);
      }
#pragma unroll
    for (int r = 0; r < 4; ++r) {
#pragma unroll
      for (int off = 1; off < 16; off <<= 1)
        mymax[r] = fmaxf(mymax[r], __shfl_xor(mymax[r], off, 16));
    }
    if (lm == 0) {
#pragma unroll
      for (int r = 0; r < 4; ++r) redA[wid*16 + quad*4 + r] = mymax[r];
    }
    __syncthreads();
    float gmax[4];
#pragma unroll
    for (int r = 0; r < 4; ++r) {
      float g = -3.0e38f;
#pragma unroll
      for (int w = 0; w < 16; ++w) g = fmaxf(g, redA[w*16 + quad*4 + r]);
      gmax[r] = g;
    }
    // ---- exp & sum (masked -> 0) ----
    float mysum[4] = {0.f, 0.f, 0.f, 0.f};
#pragma unroll
    for (int t = 0; t < 8; ++t) {
      const bool mskd = (fm >> t) & 1;
#pragma unroll
      for (int r = 0; r < 4; ++r) {
        const float e = mskd ? 0.f : __expf((sacc[t][r] - gmax[r]) * 0.125f);
        sacc[t][r] = e;
        mysum[r] += e;
      }
    }
#pragma unroll
    for (int r = 0; r < 4; ++r) {
#pragma unroll
      for (int off = 1; off < 16; off <<= 1)
        mysum[r] += __shfl_xor(mysum[r], off, 16);
    }
    if (lm == 0) {
#pragma unroll
      for (int r = 0; r < 4; ++r) redB[wid*16 + quad*4 + r] = mysum[r];
    }
    __syncthreads();
    float rw[4];
#pragma unroll
    for (int r = 0; r < 4; ++r) {
      float s = 0.f;
#pragma unroll
      for (int w = 0; w < 16; ++w) s += redB[w*16 + quad*4 + r];
      rw[r] = 1.0f / fmaxf(s, FTINY);   // denom = max(sum, tiny), matches ref
    }

    // ---- w write: wave-local slice [jbase, jbase+128).  sacc dies here. ----
#pragma unroll
    for (int t = 0; t < 8; ++t) {
#pragma unroll
      for (int r = 0; r < 4; ++r) {
        const float w = sacc[t][r] * rw[r];
        wmean[t*4 + r] += w;
        wlds[(quad*4 + r)*2056 + jbase + t*16 + lm] = f2bf(w);
      }
    }
    // ---- PV over own slice (no barrier: same-wave LDS RAW is in-order) ----
    f32x4 oacc[4];
#pragma unroll
    for (int dt = 0; dt < 4; ++dt) oacc[dt] = 0.f;
#pragma unroll
    for (int kk = 0; kk < 4; ++kk) {
      const int kl = jbase + kk*32;
      const short8 aw = *(const short8*)&wlds[lm*2056 + kl + quad*8];
#pragma unroll
      for (int dt = 0; dt < 4; ++dt) {
        const unsigned short* vr = vt + ((size_t)(n*16 + h)*64 + dt*16 + lm)*2048 + kl + quad*8;
        const short8 bv = *(const short8*)vr;
        oacc[dt] = __builtin_amdgcn_mfma_f32_16x16x32_bf16(aw, bv, oacc[dt], 0, 0, 0);
      }
    }
    // ---- reduce 16 wave-partials -> ctx ----
    __syncthreads();
    if (wid < 8) {
#pragma unroll
      for (int dt = 0; dt < 4; ++dt)
#pragma unroll
        for (int r = 0; r < 4; ++r)
          ored[(wid*16 + quad*4 + r)*68 + dt*16 + lm] = oacc[dt][r];
    }
    __syncthreads();
    if (wid >= 8) {
#pragma unroll
      for (int dt = 0; dt < 4; ++dt)
#pragma unroll
        for (int r = 0; r < 4; ++r)
          ored[((wid-8)*16 + quad*4 + r)*68 + dt*16 + lm] += oacc[dt][r];
    }
    __syncthreads();
    {
      const int r = tid >> 6, d = tid & 63;
      float s = 0.f;
#pragma unroll
      for (int w = 0; w < 8; ++w) s += ored[(w*16 + r)*68 + d];
      ctx[((size_t)(q0+r)*2 + n)*1024 + h*64 + d] = f2bf(s);
    }
    __syncthreads();
  }

  // ---- head-mean attention weights: out (L, N, L) fp32 ----
#pragma unroll
  for (int t = 0; t < 8; ++t) {
#pragma unroll
    for (int r = 0; r < 4; ++r) {
      const int row = q0 + quad*4 + r;
      const int j = jbase + t*16 + lm;
      wout[((size_t)row*2 + n)*2048 + j] = wmean[t*4 + r] * 0.0625f;
    }
  }
}

// ---------------------------------------------------------------------------
extern "C" void kernel_launch(void* const* d_in, const int* in_sizes, int n_in,
                              void* d_out, int out_size, void* d_ws, size_t ws_size,
                              hipStream_t stream) {
  const void*  x    = d_in[0];
  const int*   mask = (const int*)d_in[1];
  const float* Wq = (const float*)d_in[2];  const float* bq = (const float*)d_in[3];
  const float* Aq = (const float*)d_in[4];  const float* Bq = (const float*)d_in[5];
  const float* Wk = (const float*)d_in[6];  const float* bk = (const float*)d_in[7];
  const float* Ak = (const float*)d_in[8];  const float* Bk = (const float*)d_in[9];
  const float* Wv = (const float*)d_in[10]; const float* bv = (const float*)d_in[11];
  const float* Av = (const float*)d_in[12]; const float* Bv = (const float*)d_in[13];
  const float* Wo = (const float*)d_in[14]; const float* bo = (const float*)d_in[15];
  const float* Ao = (const float*)d_in[16]; const float* Bo = (const float*)d_in[17];

  float* outF = (float*)d_out;          // fp32: [4194304 attn | 8388608 weights]
  float* woutF = outF + 4194304;

  // d_ws: 24 MiB of bf16 internals
  unsigned short* kbuf = (unsigned short*)d_ws;   // [0, 8 MiB)
  unsigned short* vtb  = kbuf + 4194304;          // [8, 16 MiB)
  unsigned short* qbuf = vtb  + 4194304;          // [16, 24 MiB); ctx aliases
  unsigned short* ctx  = qbuf;

  // xaq/xak/xav at head of fp32 weights region (dead before wout overwrites)
  float* xaq = woutF;
  float* xak = xaq + 32768;
  float* xav = xak + 32768;
  // xao overlays kbuf (kbuf dead after attn_kernel; xao produced after it)
  float* xao = (float*)d_ws;

  xa_kernel<<<dim3(4096), dim3(256), 0, stream>>>(x, Aq, xaq, 0);
  xa_kernel<<<dim3(4096), dim3(256), 0, stream>>>(x, Ak, xak, 0);
  xa_kernel<<<dim3(4096), dim3(256), 0, stream>>>(x, Av, xav, 0);

  gemm_fused<<<dim3(32, 8, 3), dim3(256), 0, stream>>>(
      x, Wq, Wk, Wv, bq, bk, bv, xaq, xak, xav, Bq, Bk, Bv,
      qbuf, kbuf, vtb, 0, 0);

  attn_kernel<<<dim3(128, 2), dim3(1024), 0, stream>>>(qbuf, kbuf, vtb, mask, ctx, woutF);

  xa_kernel<<<dim3(4096), dim3(256), 0, stream>>>(ctx, Ao, xao, 1);

  gemm_fused<<<dim3(32, 8, 1), dim3(256), 0, stream>>>(
      ctx, Wo, Wo, Wo, bo, bo, bo, xao, xao, xao, Bo, Bo, Bo,
      outF, outF, outF, 1, 1);
}